// Round 1
// baseline (52.138 us; speedup 1.0000x reference)
//
#include <hip/hip_runtime.h>

#define NPTS 2048
#define CCH  256

// ---------------------------------------------------------------------------
// Kernel A: collapse the 3 linear layers.
//   W_eff[o][j] = sum_c W3[o][c] * (sum_d W2[c][d] * W1[d][j])
//   b_eff[o]    = sum_c W3[o][c] * (sum_d W2[c][d]*b1[d] + b2[c]) + b3[o]
// ws layout: [0 .. 767] W_eff (256x3 row-major), [768 .. 1023] b_eff
// ---------------------------------------------------------------------------
__global__ __launch_bounds__(256) void prep_kernel(
    const float* __restrict__ w1, const float* __restrict__ b1,
    const float* __restrict__ w2, const float* __restrict__ b2,
    const float* __restrict__ w3, const float* __restrict__ b3,
    float* __restrict__ ws)
{
    __shared__ float sW[CCH * 3];
    __shared__ float sB[CCH];
    int o = threadIdx.x;

    float a0 = 0.f, a1 = 0.f, a2 = 0.f, ab = 0.f;
    const float* w2r = w2 + o * CCH;
    for (int c = 0; c < CCH; ++c) {
        float w = w2r[c];
        a0 = fmaf(w, w1[c * 3 + 0], a0);
        a1 = fmaf(w, w1[c * 3 + 1], a1);
        a2 = fmaf(w, w1[c * 3 + 2], a2);
        ab = fmaf(w, b1[c], ab);
    }
    sW[o * 3 + 0] = a0;
    sW[o * 3 + 1] = a1;
    sW[o * 3 + 2] = a2;
    sB[o] = ab + b2[o];
    __syncthreads();

    float e0 = 0.f, e1 = 0.f, e2 = 0.f, eb = 0.f;
    const float* w3r = w3 + o * CCH;
    for (int c = 0; c < CCH; ++c) {
        float w = w3r[c];
        e0 = fmaf(w, sW[c * 3 + 0], e0);
        e1 = fmaf(w, sW[c * 3 + 1], e1);
        e2 = fmaf(w, sW[c * 3 + 2], e2);
        eb = fmaf(w, sB[c], eb);
    }
    ws[o * 3 + 0] = e0;
    ws[o * 3 + 1] = e1;
    ws[o * 3 + 2] = e2;
    ws[3 * CCH + o] = eb + b3[o];
}

// ---------------------------------------------------------------------------
// Kernel B: per-point octant NN select + fused affine + SPP pooling.
// One wave (64 lanes) per point; 4 waves (= 4 points) per block.
// Batch xyz staged in LDS (24 KB).
// ---------------------------------------------------------------------------
__global__ __launch_bounds__(256) void pointsift_kernel(
    const float* __restrict__ x,   // [Bp, NPTS, 3]
    const float* __restrict__ ws,  // W_eff[256*3] then b_eff[256]
    float* __restrict__ out)       // [Bp, NPTS, 21]
{
    __shared__ float sx[NPTS * 3];

    const int blocksPerBatch = NPTS / 4;   // 512
    int batch = blockIdx.x / blocksPerBatch;
    int n0    = (blockIdx.x % blocksPerBatch) * 4;
    const float* xb = x + (size_t)batch * NPTS * 3;

    // stage batch coords into LDS (1536 float4 = 24 KB)
    for (int i = threadIdx.x; i < NPTS * 3 / 4; i += 256)
        ((float4*)sx)[i] = ((const float4*)xb)[i];
    __syncthreads();

    int wave = threadIdx.x >> 6;
    int lane = threadIdx.x & 63;
    int n = n0 + wave;

    float cx = sx[n * 3 + 0], cy = sx[n * 3 + 1], cz = sx[n * 3 + 2];

    // per-lane per-octant best (strict < keeps first-min within a lane since
    // m increases monotonically per lane)
    float bd[8];
    int   bi[8];
#pragma unroll
    for (int i = 0; i < 8; ++i) { bd[i] = __builtin_inff(); bi[i] = n; }

    for (int m = lane; m < NPTS; m += 64) {
        float dx = sx[m * 3 + 0] - cx;
        float dy = sx[m * 3 + 1] - cy;
        float dz = sx[m * 3 + 2] - cz;
        // bit-match numpy: (dx*dx + dy*dy) + dz*dz, no FMA contraction
        float d2 = __fadd_rn(__fadd_rn(__fmul_rn(dx, dx), __fmul_rn(dy, dy)),
                             __fmul_rn(dz, dz));
        bool valid = (d2 > 1e-10f) && (d2 < 0.0625f);
        float d2v = valid ? d2 : __builtin_inff();
        int oct = ((dx >= 0.f) ? 4 : 0) | ((dy >= 0.f) ? 2 : 0) | ((dz >= 0.f) ? 1 : 0);
#pragma unroll
        for (int i = 0; i < 8; ++i) {
            float cand = (oct == i) ? d2v : __builtin_inff();
            bool better = cand < bd[i];
            bd[i] = better ? cand : bd[i];
            bi[i] = better ? m : bi[i];
        }
    }

    // cross-lane first-min reduce via (dist_bits << 32) | idx
    unsigned long long key[8];
#pragma unroll
    for (int i = 0; i < 8; ++i)
        key[i] = (((unsigned long long)__float_as_uint(bd[i])) << 32) |
                 (unsigned int)bi[i];
#pragma unroll
    for (int i = 0; i < 8; ++i) {
#pragma unroll
        for (int s = 32; s > 0; s >>= 1) {
            unsigned long long o = __shfl_xor(key[i], s, 64);
            key[i] = (o < key[i]) ? o : key[i];
        }
    }

    // gather relative coords (idx falls back to n -> zeros, matching diagonal)
    float gx[8], gy[8], gz[8];
#pragma unroll
    for (int k = 0; k < 8; ++k) {
        int idx = (int)(key[k] & 0xFFFFFFFFull);
        gx[k] = sx[idx * 3 + 0] - cx;
        gy[k] = sx[idx * 3 + 1] - cy;
        gz[k] = sx[idx * 3 + 2] - cz;
    }

    // fused affine: lane handles channels o0..o0+3 (so c-block j = lane>>4)
    int o0 = lane * 4;
    float w[4][3], be[4];
#pragma unroll
    for (int q = 0; q < 4; ++q) {
        w[q][0] = ws[(o0 + q) * 3 + 0];
        w[q][1] = ws[(o0 + q) * 3 + 1];
        w[q][2] = ws[(o0 + q) * 3 + 2];
        be[q]   = ws[3 * CCH + o0 + q];
    }

    // m16[i] = max over k in {2i,2i+1} and this lane's 4 channels
    float m16[4];
#pragma unroll
    for (int i = 0; i < 4; ++i) {
        float mm = -__builtin_inff();
#pragma unroll
        for (int kk = 0; kk < 2; ++kk) {
            int k = i * 2 + kk;
#pragma unroll
            for (int q = 0; q < 4; ++q) {
                float h = fmaf(gx[k], w[q][0],
                          fmaf(gy[k], w[q][1],
                          fmaf(gz[k], w[q][2], be[q])));
                mm = fmaxf(mm, h);
            }
        }
        m16[i] = mm;
    }

    // reduce within 16-lane channel groups -> bins16[i][j], j = lane>>4
#pragma unroll
    for (int i = 0; i < 4; ++i) {
#pragma unroll
        for (int s = 1; s < 16; s <<= 1)
            m16[i] = fmaxf(m16[i], __shfl_xor(m16[i], s, 64));
    }
    // t: max over {j, j^1} (128-channel halves); u: global over channels
    float t[4], u[4];
#pragma unroll
    for (int i = 0; i < 4; ++i) {
        t[i] = fmaxf(m16[i], __shfl_xor(m16[i], 16, 64));
        u[i] = fmaxf(t[i], __shfl_xor(t[i], 32, 64));
    }

    float* op = out + ((size_t)batch * NPTS + n) * 21;
    if ((lane & 15) == 0) {
        int j = lane >> 4;
#pragma unroll
        for (int i = 0; i < 4; ++i)
            op[i * 4 + j] = m16[i];           // 4x4 bins: out[i*4+j]
    }
    if (lane == 0 || lane == 32) {
        int j2 = lane >> 5;                    // 2x2 bins
        op[16 + 0 * 2 + j2] = fmaxf(t[0], t[1]);
        op[16 + 1 * 2 + j2] = fmaxf(t[2], t[3]);
    }
    if (lane == 0) {                           // 1x1 bin
        op[20] = fmaxf(fmaxf(u[0], u[1]), fmaxf(u[2], u[3]));
    }
}

extern "C" void kernel_launch(void* const* d_in, const int* in_sizes, int n_in,
                              void* d_out, int out_size, void* d_ws, size_t ws_size,
                              hipStream_t stream) {
    const float* x  = (const float*)d_in[0];
    const float* w1 = (const float*)d_in[1];
    const float* b1 = (const float*)d_in[2];
    const float* w2 = (const float*)d_in[3];
    const float* b2 = (const float*)d_in[4];
    const float* w3 = (const float*)d_in[5];
    const float* b3 = (const float*)d_in[6];
    float* out = (float*)d_out;
    float* ws  = (float*)d_ws;

    prep_kernel<<<1, 256, 0, stream>>>(w1, b1, w2, b2, w3, b3, ws);

    int Bp = in_sizes[0] / (NPTS * 3);         // B*T = 4
    pointsift_kernel<<<Bp * (NPTS / 4), 256, 0, stream>>>(x, ws, out);
}

// Round 2
// 49.141 us; speedup vs baseline: 1.0610x; 1.0610x over previous
//
#include <hip/hip_runtime.h>

#define NPTS 2048
#define CCH  256
#define CAP  320   // per-wave compaction capacity; E[valid]~134, sigma~11; fallback if exceeded

// ---------------------------------------------------------------------------
// Kernel A: collapse the 3 linear layers (1024 threads, split-K over 4 quarters).
//   W_eff = W3*(W2*W1), b_eff = W3*(W2*b1 + b2) + b3
// ws layout: [0..767] W_eff (256x3 row-major), [768..1023] b_eff
// ---------------------------------------------------------------------------
__global__ __launch_bounds__(1024) void prep_kernel(
    const float* __restrict__ w1, const float* __restrict__ b1,
    const float* __restrict__ w2, const float* __restrict__ b2,
    const float* __restrict__ w3, const float* __restrict__ b3,
    float* __restrict__ ws)
{
    __shared__ float4 part4[1024];      // 16 KB partials
    __shared__ float  sW[CCH * 3];
    __shared__ float  sB[CCH];
    int o = threadIdx.x & 255;
    int q = threadIdx.x >> 8;           // 0..3, each sums 64 c's

    // stage 1: sW = W2*W1, sB = W2*b1 + b2
    {
        float a0 = 0.f, a1 = 0.f, a2 = 0.f, ab = 0.f;
        const float* w2r = w2 + o * CCH;
        for (int c = q * 64; c < q * 64 + 64; ++c) {
            float w = w2r[c];
            a0 = fmaf(w, w1[c * 3 + 0], a0);
            a1 = fmaf(w, w1[c * 3 + 1], a1);
            a2 = fmaf(w, w1[c * 3 + 2], a2);
            ab = fmaf(w, b1[c], ab);
        }
        part4[threadIdx.x] = make_float4(a0, a1, a2, ab);
    }
    __syncthreads();
    if (q == 0) {
        float4 p0 = part4[o], p1 = part4[o + 256], p2 = part4[o + 512], p3 = part4[o + 768];
        sW[o * 3 + 0] = (p0.x + p1.x) + (p2.x + p3.x);
        sW[o * 3 + 1] = (p0.y + p1.y) + (p2.y + p3.y);
        sW[o * 3 + 2] = (p0.z + p1.z) + (p2.z + p3.z);
        sB[o] = (p0.w + p1.w) + (p2.w + p3.w) + b2[o];
    }
    __syncthreads();

    // stage 2: W_eff = W3*sW, b_eff = W3*sB + b3
    {
        float e0 = 0.f, e1 = 0.f, e2 = 0.f, eb = 0.f;
        const float* w3r = w3 + o * CCH;
        for (int c = q * 64; c < q * 64 + 64; ++c) {
            float w = w3r[c];
            e0 = fmaf(w, sW[c * 3 + 0], e0);
            e1 = fmaf(w, sW[c * 3 + 1], e1);
            e2 = fmaf(w, sW[c * 3 + 2], e2);
            eb = fmaf(w, sB[c], eb);
        }
        part4[threadIdx.x] = make_float4(e0, e1, e2, eb);
    }
    __syncthreads();
    if (q == 0) {
        float4 p0 = part4[o], p1 = part4[o + 256], p2 = part4[o + 512], p3 = part4[o + 768];
        ws[o * 3 + 0] = (p0.x + p1.x) + (p2.x + p3.x);
        ws[o * 3 + 1] = (p0.y + p1.y) + (p2.y + p3.y);
        ws[o * 3 + 2] = (p0.z + p1.z) + (p2.z + p3.z);
        ws[3 * CCH + o] = (p0.w + p1.w) + (p2.w + p3.w) + b3[o];
    }
}

// ---------------------------------------------------------------------------
// Kernel B: per-point octant NN select + fused affine + SPP pooling.
// 512 threads = 8 waves = 8 points per block; batch coords staged once (24 KB).
// Pass 1: validity scan + per-wave compaction (ballot/mbcnt, no barriers).
// Pass 2: 8-octant argmin over ~134 compacted candidates.
// ---------------------------------------------------------------------------
__global__ __launch_bounds__(512) void pointsift_kernel(
    const float* __restrict__ x,   // [Bp, NPTS, 3]
    const float* __restrict__ ws,  // W_eff[256*3] then b_eff[256]
    float* __restrict__ out)       // [Bp, NPTS, 21]
{
    __shared__ float sx[NPTS * 3];                 // 24 KB
    __shared__ unsigned short slist[8][CAP];       // 5 KB

    int batch = blockIdx.x >> 8;                   // 256 blocks per batch
    int n0    = (blockIdx.x & 255) * 8;
    const float* xb = x + (size_t)batch * NPTS * 3;

    for (int i = threadIdx.x; i < NPTS * 3 / 4; i += 512)
        ((float4*)sx)[i] = ((const float4*)xb)[i];
    __syncthreads();

    int wave = threadIdx.x >> 6;
    int lane = threadIdx.x & 63;
    int n = n0 + wave;

    float cx = sx[n * 3 + 0], cy = sx[n * 3 + 1], cz = sx[n * 3 + 2];

    // ---- pass 1: validity + wave compaction ----
    unsigned cnt = 0;
    for (int m = lane; m < NPTS; m += 64) {
        float dx = sx[m * 3 + 0] - cx;
        float dy = sx[m * 3 + 1] - cy;
        float dz = sx[m * 3 + 2] - cz;
        // bit-match numpy: (dx*dx + dy*dy) + dz*dz, no FMA contraction
        float d2 = __fadd_rn(__fadd_rn(__fmul_rn(dx, dx), __fmul_rn(dy, dy)),
                             __fmul_rn(dz, dz));
        bool valid = (d2 > 1e-10f) && (d2 < 0.0625f);
        unsigned long long mask = __ballot(valid);
        unsigned below = __builtin_amdgcn_mbcnt_hi(
            (unsigned)(mask >> 32),
            __builtin_amdgcn_mbcnt_lo((unsigned)mask, 0u));
        unsigned pos = cnt + below;
        if (valid && pos < CAP) slist[wave][pos] = (unsigned short)m;
        cnt += (unsigned)__popcll(mask);
    }

    // ---- per-octant best (strict < keeps first-min; m ascending per lane) ----
    float bd[8];
    int   bi[8];
#pragma unroll
    for (int i = 0; i < 8; ++i) { bd[i] = __builtin_inff(); bi[i] = n; }

    if (cnt <= CAP) {
        int cn = (int)cnt;
        for (int t = lane; t < cn; t += 64) {
            int m = slist[wave][t];
            float dx = sx[m * 3 + 0] - cx;
            float dy = sx[m * 3 + 1] - cy;
            float dz = sx[m * 3 + 2] - cz;
            float d2 = __fadd_rn(__fadd_rn(__fmul_rn(dx, dx), __fmul_rn(dy, dy)),
                                 __fmul_rn(dz, dz));
            // exact octant per reference: trunc(d+1.0) in {0,1}
            int oct = 4 * (int)(dx + 1.0f) + 2 * (int)(dy + 1.0f) + (int)(dz + 1.0f);
#pragma unroll
            for (int i = 0; i < 8; ++i) {
                bool upd = (oct == i) && (d2 < bd[i]);
                bd[i] = upd ? d2 : bd[i];
                bi[i] = upd ? m : bi[i];
            }
        }
    } else {
        // never expected for these inputs; guarantees correctness regardless
        for (int m = lane; m < NPTS; m += 64) {
            float dx = sx[m * 3 + 0] - cx;
            float dy = sx[m * 3 + 1] - cy;
            float dz = sx[m * 3 + 2] - cz;
            float d2 = __fadd_rn(__fadd_rn(__fmul_rn(dx, dx), __fmul_rn(dy, dy)),
                                 __fmul_rn(dz, dz));
            bool valid = (d2 > 1e-10f) && (d2 < 0.0625f);
            int oct = 4 * (int)(dx + 1.0f) + 2 * (int)(dy + 1.0f) + (int)(dz + 1.0f);
#pragma unroll
            for (int i = 0; i < 8; ++i) {
                bool upd = valid && (oct == i) && (d2 < bd[i]);
                bd[i] = upd ? d2 : bd[i];
                bi[i] = upd ? m : bi[i];
            }
        }
    }

    // ---- cross-lane first-min reduce via (dist_bits << 32) | idx ----
    unsigned long long key[8];
#pragma unroll
    for (int i = 0; i < 8; ++i)
        key[i] = (((unsigned long long)__float_as_uint(bd[i])) << 32) |
                 (unsigned int)bi[i];
#pragma unroll
    for (int i = 0; i < 8; ++i) {
#pragma unroll
        for (int s = 32; s > 0; s >>= 1) {
            unsigned long long o = __shfl_xor(key[i], s, 64);
            key[i] = (o < key[i]) ? o : key[i];
        }
    }
    int nidx[8];
#pragma unroll
    for (int i = 0; i < 8; ++i) nidx[i] = (int)(key[i] & 0xFFFFFFFFull);

    // ---- fused affine + SPP: lane handles channels o0..o0+3 ----
    int o0 = lane * 4;
    float w[4][3], be[4];
#pragma unroll
    for (int q = 0; q < 4; ++q) {
        w[q][0] = ws[(o0 + q) * 3 + 0];
        w[q][1] = ws[(o0 + q) * 3 + 1];
        w[q][2] = ws[(o0 + q) * 3 + 2];
        be[q]   = ws[3 * CCH + o0 + q];
    }

    float m16[4];
#pragma unroll
    for (int i = 0; i < 4; ++i) m16[i] = -__builtin_inff();
#pragma unroll
    for (int k = 0; k < 8; ++k) {
        int idx = nidx[k];
        float gx = sx[idx * 3 + 0] - cx;
        float gy = sx[idx * 3 + 1] - cy;
        float gz = sx[idx * 3 + 2] - cz;
#pragma unroll
        for (int q = 0; q < 4; ++q) {
            float h = fmaf(gx, w[q][0], fmaf(gy, w[q][1], fmaf(gz, w[q][2], be[q])));
            m16[k >> 1] = fmaxf(m16[k >> 1], h);
        }
    }

    // reduce within 16-lane channel groups -> 4x4 bins; then 2x2 and 1x1
#pragma unroll
    for (int i = 0; i < 4; ++i) {
#pragma unroll
        for (int s = 1; s < 16; s <<= 1)
            m16[i] = fmaxf(m16[i], __shfl_xor(m16[i], s, 64));
    }
    float t[4], u[4];
#pragma unroll
    for (int i = 0; i < 4; ++i) {
        t[i] = fmaxf(m16[i], __shfl_xor(m16[i], 16, 64));
        u[i] = fmaxf(t[i], __shfl_xor(t[i], 32, 64));
    }

    float* op = out + ((size_t)batch * NPTS + n) * 21;
    if ((lane & 15) == 0) {
        int j = lane >> 4;
#pragma unroll
        for (int i = 0; i < 4; ++i)
            op[i * 4 + j] = m16[i];
    }
    if (lane == 0 || lane == 32) {
        int j2 = lane >> 5;
        op[16 + 0 * 2 + j2] = fmaxf(t[0], t[1]);
        op[16 + 1 * 2 + j2] = fmaxf(t[2], t[3]);
    }
    if (lane == 0) {
        op[20] = fmaxf(fmaxf(u[0], u[1]), fmaxf(u[2], u[3]));
    }
}

extern "C" void kernel_launch(void* const* d_in, const int* in_sizes, int n_in,
                              void* d_out, int out_size, void* d_ws, size_t ws_size,
                              hipStream_t stream) {
    const float* x  = (const float*)d_in[0];
    const float* w1 = (const float*)d_in[1];
    const float* b1 = (const float*)d_in[2];
    const float* w2 = (const float*)d_in[3];
    const float* b2 = (const float*)d_in[4];
    const float* w3 = (const float*)d_in[5];
    const float* b3 = (const float*)d_in[6];
    float* out = (float*)d_out;
    float* ws  = (float*)d_ws;

    prep_kernel<<<1, 1024, 0, stream>>>(w1, b1, w2, b2, w3, b3, ws);

    int Bp = in_sizes[0] / (NPTS * 3);             // B*T = 4
    pointsift_kernel<<<Bp * (NPTS / 8), 512, 0, stream>>>(x, ws, out);
}

// Round 3
// 31.154 us; speedup vs baseline: 1.6736x; 1.5773x over previous
//
#include <hip/hip_runtime.h>

#define NPTS 2048
#define CCH  256
#define CAP  320   // per-wave compaction capacity; E[valid]~134, sigma~11; fallback if exceeded

// ws layout (floats): [0..767] W_eff (256x3), [768..1023] b_eff, [1024..2047] tmp (256x float4)

// ---------------------------------------------------------------------------
// prep1: tmp[o] = { (W2*W1)[o][0..2], (W2*b1)[o] + b2[o] }   -- 256 blocks
// coalesced: thread c reads w2[o*256+c]
// ---------------------------------------------------------------------------
__global__ __launch_bounds__(256) void prep1_kernel(
    const float* __restrict__ w1, const float* __restrict__ b1,
    const float* __restrict__ w2, const float* __restrict__ b2,
    float* __restrict__ ws)
{
    __shared__ float4 buf[256];
    int o = blockIdx.x, c = threadIdx.x;
    float p = w2[o * CCH + c];
    buf[c] = make_float4(p * w1[c * 3 + 0], p * w1[c * 3 + 1],
                         p * w1[c * 3 + 2], p * b1[c]);
    __syncthreads();
    for (int s = 128; s > 0; s >>= 1) {
        if (c < s) {
            float4 a = buf[c], b = buf[c + s];
            buf[c] = make_float4(a.x + b.x, a.y + b.y, a.z + b.z, a.w + b.w);
        }
        __syncthreads();
    }
    if (c == 0) {
        float4 v = buf[0];
        v.w += b2[o];
        ((float4*)(ws + 4 * CCH))[o] = v;
    }
}

// ---------------------------------------------------------------------------
// prep2: W_eff[o] = (W3*tmpW)[o], b_eff[o] = (W3*tmpB)[o] + b3[o]
// ---------------------------------------------------------------------------
__global__ __launch_bounds__(256) void prep2_kernel(
    const float* __restrict__ w3, const float* __restrict__ b3,
    float* __restrict__ ws)
{
    __shared__ float4 buf[256];
    int o = blockIdx.x, c = threadIdx.x;
    float p = w3[o * CCH + c];
    float4 t = ((const float4*)(ws + 4 * CCH))[c];
    buf[c] = make_float4(p * t.x, p * t.y, p * t.z, p * t.w);
    __syncthreads();
    for (int s = 128; s > 0; s >>= 1) {
        if (c < s) {
            float4 a = buf[c], b = buf[c + s];
            buf[c] = make_float4(a.x + b.x, a.y + b.y, a.z + b.z, a.w + b.w);
        }
        __syncthreads();
    }
    if (c == 0) {
        float4 v = buf[0];
        ws[o * 3 + 0] = v.x;
        ws[o * 3 + 1] = v.y;
        ws[o * 3 + 2] = v.z;
        ws[3 * CCH + o] = v.w + b3[o];
    }
}

// ---------------------------------------------------------------------------
// Kernel B: per-point octant NN select + fused affine + SPP pooling.
// 512 threads = 8 waves = 8 points per block; batch coords staged once (32 KB
// as float4). Pass 1: validity scan + per-wave compaction. Pass 2: 8-octant
// argmin over ~134 compacted candidates. f32 butterfly min + exact tie-break.
// ---------------------------------------------------------------------------
__global__ __launch_bounds__(512, 8) void pointsift_kernel(
    const float* __restrict__ x,   // [Bp, NPTS, 3]
    const float* __restrict__ ws,  // W_eff[256*3] then b_eff[256]
    float* __restrict__ out)       // [Bp, NPTS, 21]
{
    __shared__ float4 sx4[NPTS];                   // 32 KB
    __shared__ unsigned short slist[8][CAP];       // 5 KB

    int batch = blockIdx.x >> 8;                   // 256 blocks per batch
    int n0    = (blockIdx.x & 255) * 8;
    const float* xb = x + (size_t)batch * NPTS * 3;

    for (int i = threadIdx.x; i < NPTS; i += 512)
        sx4[i] = make_float4(xb[3 * i + 0], xb[3 * i + 1], xb[3 * i + 2], 0.f);
    __syncthreads();

    int wave = threadIdx.x >> 6;
    int lane = threadIdx.x & 63;
    int n = n0 + wave;

    float4 cp = sx4[n];
    float cx = cp.x, cy = cp.y, cz = cp.z;

    // ---- pass 1: validity + wave compaction ----
    unsigned cnt = 0;
#pragma unroll 4
    for (int m = lane; m < NPTS; m += 64) {
        float4 p = sx4[m];
        float dx = p.x - cx, dy = p.y - cy, dz = p.z - cz;
        // bit-match numpy: (dx*dx + dy*dy) + dz*dz, no FMA contraction
        float d2 = __fadd_rn(__fadd_rn(__fmul_rn(dx, dx), __fmul_rn(dy, dy)),
                             __fmul_rn(dz, dz));
        bool valid = (d2 > 1e-10f) && (d2 < 0.0625f);
        unsigned long long mask = __ballot(valid);
        unsigned below = __builtin_amdgcn_mbcnt_hi(
            (unsigned)(mask >> 32),
            __builtin_amdgcn_mbcnt_lo((unsigned)mask, 0u));
        unsigned pos = cnt + below;
        if (valid && pos < CAP) slist[wave][pos] = (unsigned short)m;
        cnt += (unsigned)__popcll(mask);
    }

    // ---- per-octant best (strict < keeps first-min; m ascending per lane) ----
    float bd[8];
    int   bi[8];
#pragma unroll
    for (int i = 0; i < 8; ++i) { bd[i] = __builtin_inff(); bi[i] = n; }

    if (cnt <= CAP) {
        int cn = (int)cnt;
        for (int t = lane; t < cn; t += 64) {
            int m = slist[wave][t];
            float4 p = sx4[m];
            float dx = p.x - cx, dy = p.y - cy, dz = p.z - cz;
            float d2 = __fadd_rn(__fadd_rn(__fmul_rn(dx, dx), __fmul_rn(dy, dy)),
                                 __fmul_rn(dz, dz));
            // exact octant per reference: trunc(d+1.0) in {0,1}
            int oct = 4 * (int)(dx + 1.0f) + 2 * (int)(dy + 1.0f) + (int)(dz + 1.0f);
#pragma unroll
            for (int i = 0; i < 8; ++i) {
                bool upd = (oct == i) && (d2 < bd[i]);
                bd[i] = upd ? d2 : bd[i];
                bi[i] = upd ? m : bi[i];
            }
        }
    } else {
        // never expected for these inputs; guarantees correctness regardless
        for (int m = lane; m < NPTS; m += 64) {
            float4 p = sx4[m];
            float dx = p.x - cx, dy = p.y - cy, dz = p.z - cz;
            float d2 = __fadd_rn(__fadd_rn(__fmul_rn(dx, dx), __fmul_rn(dy, dy)),
                                 __fmul_rn(dz, dz));
            bool valid = (d2 > 1e-10f) && (d2 < 0.0625f);
            int oct = 4 * (int)(dx + 1.0f) + 2 * (int)(dy + 1.0f) + (int)(dz + 1.0f);
#pragma unroll
            for (int i = 0; i < 8; ++i) {
                bool upd = valid && (oct == i) && (d2 < bd[i]);
                bd[i] = upd ? d2 : bd[i];
                bi[i] = upd ? m : bi[i];
            }
        }
    }

    // ---- cross-lane argmin: f32 butterfly min, exact first-min tie-break ----
    int nidx[8];
#pragma unroll
    for (int i = 0; i < 8; ++i) {
        float mv = bd[i];
#pragma unroll
        for (int s = 32; s > 0; s >>= 1)
            mv = fminf(mv, __shfl_xor(mv, s, 64));
        unsigned long long mk = __ballot(bd[i] == mv);   // wave-uniform mask
        if (__popcll(mk) == 1) {
            nidx[i] = __shfl(bi[i], (int)__builtin_ctzll(mk), 64);
        } else {
            // ties (or empty octant: mv=inf, all lanes match, bi=n everywhere)
            int mm = (bd[i] == mv) ? bi[i] : 0x7FFFFFFF;
#pragma unroll
            for (int s = 32; s > 0; s >>= 1) {
                int o = __shfl_xor(mm, s, 64);
                mm = o < mm ? o : mm;
            }
            nidx[i] = mm;
        }
    }

    // ---- fused affine + SPP: lane handles channels o0..o0+3 ----
    int o0 = lane * 4;
    float w[4][3], be[4];
#pragma unroll
    for (int q = 0; q < 4; ++q) {
        w[q][0] = ws[(o0 + q) * 3 + 0];
        w[q][1] = ws[(o0 + q) * 3 + 1];
        w[q][2] = ws[(o0 + q) * 3 + 2];
        be[q]   = ws[3 * CCH + o0 + q];
    }

    float m16[4];
#pragma unroll
    for (int i = 0; i < 4; ++i) m16[i] = -__builtin_inff();
#pragma unroll
    for (int k = 0; k < 8; ++k) {
        float4 p = sx4[nidx[k]];
        float gx = p.x - cx, gy = p.y - cy, gz = p.z - cz;
#pragma unroll
        for (int q = 0; q < 4; ++q) {
            float h = fmaf(gx, w[q][0], fmaf(gy, w[q][1], fmaf(gz, w[q][2], be[q])));
            m16[k >> 1] = fmaxf(m16[k >> 1], h);
        }
    }

    // reduce within 16-lane channel groups -> 4x4 bins; then 2x2 and 1x1
#pragma unroll
    for (int i = 0; i < 4; ++i) {
#pragma unroll
        for (int s = 1; s < 16; s <<= 1)
            m16[i] = fmaxf(m16[i], __shfl_xor(m16[i], s, 64));
    }
    float t[4], u[4];
#pragma unroll
    for (int i = 0; i < 4; ++i) {
        t[i] = fmaxf(m16[i], __shfl_xor(m16[i], 16, 64));
        u[i] = fmaxf(t[i], __shfl_xor(t[i], 32, 64));
    }

    float* op = out + ((size_t)batch * NPTS + n) * 21;
    if ((lane & 15) == 0) {
        int j = lane >> 4;
#pragma unroll
        for (int i = 0; i < 4; ++i)
            op[i * 4 + j] = m16[i];
    }
    if (lane == 0 || lane == 32) {
        int j2 = lane >> 5;
        op[16 + 0 * 2 + j2] = fmaxf(t[0], t[1]);
        op[16 + 1 * 2 + j2] = fmaxf(t[2], t[3]);
    }
    if (lane == 0) {
        op[20] = fmaxf(fmaxf(u[0], u[1]), fmaxf(u[2], u[3]));
    }
}

extern "C" void kernel_launch(void* const* d_in, const int* in_sizes, int n_in,
                              void* d_out, int out_size, void* d_ws, size_t ws_size,
                              hipStream_t stream) {
    const float* x  = (const float*)d_in[0];
    const float* w1 = (const float*)d_in[1];
    const float* b1 = (const float*)d_in[2];
    const float* w2 = (const float*)d_in[3];
    const float* b2 = (const float*)d_in[4];
    const float* w3 = (const float*)d_in[5];
    const float* b3 = (const float*)d_in[6];
    float* out = (float*)d_out;
    float* ws  = (float*)d_ws;

    prep1_kernel<<<CCH, CCH, 0, stream>>>(w1, b1, w2, b2, ws);
    prep2_kernel<<<CCH, CCH, 0, stream>>>(w3, b3, ws);

    int Bp = in_sizes[0] / (NPTS * 3);             // B*T = 4
    pointsift_kernel<<<Bp * (NPTS / 8), 512, 0, stream>>>(x, ws, out);
}

// Round 4
// 30.092 us; speedup vs baseline: 1.7326x; 1.0353x over previous
//
#include <hip/hip_runtime.h>

#define NPTS 2048
#define CCH  256
#define CAP  320   // per-wave compaction capacity; E[valid]~134, sigma~11; fallback if exceeded

// ---- DPP cross-lane helpers (VALU pipe, no LDS) ----
// quad_perm xor1 = 0xB1, xor2 = 0x4E, row_half_mirror = 0x141, row_mirror = 0x140
template <int CTRL>
__device__ __forceinline__ float dppf(float v) {
    return __int_as_float(__builtin_amdgcn_update_dpp(
        0, __float_as_int(v), CTRL, 0xF, 0xF, true));
}
// max over each 16-lane row (result in every lane of the row)
__device__ __forceinline__ float row16_max(float v) {
    v = fmaxf(v, dppf<0xB1>(v));
    v = fmaxf(v, dppf<0x4E>(v));
    v = fmaxf(v, dppf<0x141>(v));
    v = fmaxf(v, dppf<0x140>(v));
    return v;
}
__device__ __forceinline__ float row16_min(float v) {
    v = fminf(v, dppf<0xB1>(v));
    v = fminf(v, dppf<0x4E>(v));
    v = fminf(v, dppf<0x141>(v));
    v = fminf(v, dppf<0x140>(v));
    return v;
}
__device__ __forceinline__ float row16_sum(float v) {
    v += dppf<0xB1>(v);
    v += dppf<0x4E>(v);
    v += dppf<0x141>(v);
    v += dppf<0x140>(v);
    return v;
}
__device__ __forceinline__ float wave_sum(float v) {
    v = row16_sum(v);
    v += __shfl_xor(v, 16, 64);
    v += __shfl_xor(v, 32, 64);
    return v;
}

// ws layout (floats): [0..767] W_eff (256x3), [768..1023] b_eff, [1024..2047] tmp (256x float4)

// ---------------------------------------------------------------------------
// prep1: tmp[o] = { (W2*W1)[o][0..2], (W2*b1)[o] + b2[o] }   -- 256 blocks
// ---------------------------------------------------------------------------
__global__ __launch_bounds__(256) void prep1_kernel(
    const float* __restrict__ w1, const float* __restrict__ b1,
    const float* __restrict__ w2, const float* __restrict__ b2,
    float* __restrict__ ws)
{
    __shared__ float4 wsum[4];
    int o = blockIdx.x, c = threadIdx.x;
    float p = w2[o * CCH + c];
    float vx = wave_sum(p * w1[c * 3 + 0]);
    float vy = wave_sum(p * w1[c * 3 + 1]);
    float vz = wave_sum(p * w1[c * 3 + 2]);
    float vw = wave_sum(p * b1[c]);
    if ((c & 63) == 0) wsum[c >> 6] = make_float4(vx, vy, vz, vw);
    __syncthreads();
    if (c == 0) {
        float4 a = wsum[0], b = wsum[1], d = wsum[2], e = wsum[3];
        float4 r = make_float4((a.x + b.x) + (d.x + e.x), (a.y + b.y) + (d.y + e.y),
                               (a.z + b.z) + (d.z + e.z), (a.w + b.w) + (d.w + e.w));
        r.w += b2[o];
        ((float4*)(ws + 4 * CCH))[o] = r;
    }
}

// ---------------------------------------------------------------------------
// prep2: W_eff[o] = (W3*tmpW)[o], b_eff[o] = (W3*tmpB)[o] + b3[o]
// ---------------------------------------------------------------------------
__global__ __launch_bounds__(256) void prep2_kernel(
    const float* __restrict__ w3, const float* __restrict__ b3,
    float* __restrict__ ws)
{
    __shared__ float4 wsum[4];
    int o = blockIdx.x, c = threadIdx.x;
    float p = w3[o * CCH + c];
    float4 t = ((const float4*)(ws + 4 * CCH))[c];
    float vx = wave_sum(p * t.x);
    float vy = wave_sum(p * t.y);
    float vz = wave_sum(p * t.z);
    float vw = wave_sum(p * t.w);
    if ((c & 63) == 0) wsum[c >> 6] = make_float4(vx, vy, vz, vw);
    __syncthreads();
    if (c == 0) {
        float4 a = wsum[0], b = wsum[1], d = wsum[2], e = wsum[3];
        ws[o * 3 + 0] = (a.x + b.x) + (d.x + e.x);
        ws[o * 3 + 1] = (a.y + b.y) + (d.y + e.y);
        ws[o * 3 + 2] = (a.z + b.z) + (d.z + e.z);
        ws[3 * CCH + o] = (a.w + b.w) + (d.w + e.w) + b3[o];
    }
}

// ---------------------------------------------------------------------------
// Kernel B: per-point octant NN select + fused affine + SPP pooling.
// 512 threads = 8 waves = 8 points/block. Pass-1 reads coords from GLOBAL
// (L1-resident 24 KB/batch, VMEM pipe); LDS keeps only slist + staged coords
// for the random-access pass-2/gather. Reductions via DPP (VALU pipe).
// batch = blockIdx.x & 3 so a CU's resident blocks share one batch in L1.
// ---------------------------------------------------------------------------
__global__ __launch_bounds__(512, 8) void pointsift_kernel(
    const float* __restrict__ x,   // [Bp, NPTS, 3]
    const float* __restrict__ ws,  // W_eff[256*3] then b_eff[256]
    float* __restrict__ out)       // [Bp, NPTS, 21]
{
    __shared__ float4 sx4[NPTS];                   // 32 KB
    __shared__ unsigned short slist[8][CAP];       // 5 KB

    int batch = blockIdx.x & 3;
    int n0    = (blockIdx.x >> 2) * 8;
    const float* xb = x + (size_t)batch * NPTS * 3;

    // stage coords into LDS for pass-2/gather (pass-1 reads global instead)
    for (int i = threadIdx.x; i < NPTS; i += 512) {
        float3 p = *(const float3*)(xb + 3 * i);
        sx4[i] = make_float4(p.x, p.y, p.z, 0.f);
    }

    int wave = threadIdx.x >> 6;
    int lane = threadIdx.x & 63;
    int n = n0 + wave;

    float3 cpt = *(const float3*)(xb + 3 * n);
    float cx = cpt.x, cy = cpt.y, cz = cpt.z;

    // ---- pass 1: validity + wave compaction (global reads, VMEM pipe) ----
    unsigned cnt = 0;
#pragma unroll 4
    for (int m = lane; m < NPTS; m += 64) {
        float3 p = *(const float3*)(xb + 3 * m);
        float dx = p.x - cx, dy = p.y - cy, dz = p.z - cz;
        // bit-match numpy: (dx*dx + dy*dy) + dz*dz, no FMA contraction
        float d2 = __fadd_rn(__fadd_rn(__fmul_rn(dx, dx), __fmul_rn(dy, dy)),
                             __fmul_rn(dz, dz));
        bool valid = (d2 > 1e-10f) && (d2 < 0.0625f);
        unsigned long long mask = __ballot(valid);
        unsigned below = __builtin_amdgcn_mbcnt_hi(
            (unsigned)(mask >> 32),
            __builtin_amdgcn_mbcnt_lo((unsigned)mask, 0u));
        unsigned pos = cnt + below;
        if (valid && pos < CAP) slist[wave][pos] = (unsigned short)m;
        cnt += (unsigned)__popcll(mask);
    }

    __syncthreads();   // sx4 staged (slist is per-wave, already visible)

    // ---- pass 2: per-octant best over compacted candidates ----
    float bd[8];
    int   bi[8];
#pragma unroll
    for (int i = 0; i < 8; ++i) { bd[i] = __builtin_inff(); bi[i] = n; }

    if (cnt <= CAP) {
        int cn = (int)cnt;
        for (int t = lane; t < cn; t += 64) {
            int m = slist[wave][t];
            float4 p = sx4[m];
            float dx = p.x - cx, dy = p.y - cy, dz = p.z - cz;
            float d2 = __fadd_rn(__fadd_rn(__fmul_rn(dx, dx), __fmul_rn(dy, dy)),
                                 __fmul_rn(dz, dz));
            // exact octant per reference: trunc(d+1.0) in {0,1}
            int oct = 4 * (int)(dx + 1.0f) + 2 * (int)(dy + 1.0f) + (int)(dz + 1.0f);
#pragma unroll
            for (int i = 0; i < 8; ++i) {
                bool upd = (oct == i) && (d2 < bd[i]);
                bd[i] = upd ? d2 : bd[i];
                bi[i] = upd ? m : bi[i];
            }
        }
    } else {
        // never expected for these inputs; guarantees correctness regardless
        for (int m = lane; m < NPTS; m += 64) {
            float4 p = sx4[m];
            float dx = p.x - cx, dy = p.y - cy, dz = p.z - cz;
            float d2 = __fadd_rn(__fadd_rn(__fmul_rn(dx, dx), __fmul_rn(dy, dy)),
                                 __fmul_rn(dz, dz));
            bool valid = (d2 > 1e-10f) && (d2 < 0.0625f);
            int oct = 4 * (int)(dx + 1.0f) + 2 * (int)(dy + 1.0f) + (int)(dz + 1.0f);
#pragma unroll
            for (int i = 0; i < 8; ++i) {
                bool upd = valid && (oct == i) && (d2 < bd[i]);
                bd[i] = upd ? d2 : bd[i];
                bi[i] = upd ? m : bi[i];
            }
        }
    }

    // ---- cross-lane argmin: DPP min + 2 swizzles; first-min tie-break ----
    int nidx[8];
#pragma unroll
    for (int i = 0; i < 8; ++i) {
        float mv = row16_min(bd[i]);
        mv = fminf(mv, __shfl_xor(mv, 16, 64));
        mv = fminf(mv, __shfl_xor(mv, 32, 64));
        unsigned long long mk = __ballot(bd[i] == mv);   // wave-uniform
        if (__popcll(mk) == 1) {
            nidx[i] = __builtin_amdgcn_readlane(bi[i], (int)__builtin_ctzll(mk));
        } else {
            // ties (or empty octant: mv=inf, all lanes match, bi=n everywhere)
            int mm = (bd[i] == mv) ? bi[i] : 0x7FFFFFFF;
#pragma unroll
            for (int s = 32; s > 0; s >>= 1) {
                int o = __shfl_xor(mm, s, 64);
                mm = o < mm ? o : mm;
            }
            nidx[i] = mm;
        }
    }

    // ---- fused affine + SPP: lane handles channels o0..o0+3 ----
    int o0 = lane * 4;
    float w[4][3], be[4];
#pragma unroll
    for (int q = 0; q < 4; ++q) {
        w[q][0] = ws[(o0 + q) * 3 + 0];
        w[q][1] = ws[(o0 + q) * 3 + 1];
        w[q][2] = ws[(o0 + q) * 3 + 2];
        be[q]   = ws[3 * CCH + o0 + q];
    }

    float m16[4];
#pragma unroll
    for (int i = 0; i < 4; ++i) m16[i] = -__builtin_inff();
#pragma unroll
    for (int k = 0; k < 8; ++k) {
        float4 p = sx4[nidx[k]];
        float gx = p.x - cx, gy = p.y - cy, gz = p.z - cz;
#pragma unroll
        for (int q = 0; q < 4; ++q) {
            float h = fmaf(gx, w[q][0], fmaf(gy, w[q][1], fmaf(gz, w[q][2], be[q])));
            m16[k >> 1] = fmaxf(m16[k >> 1], h);
        }
    }

    // 16-lane channel-group max via DPP; cross-group via 2 swizzles
    float t[4], u[4];
#pragma unroll
    for (int i = 0; i < 4; ++i) {
        m16[i] = row16_max(m16[i]);
        t[i] = fmaxf(m16[i], __shfl_xor(m16[i], 16, 64));
        u[i] = fmaxf(t[i], __shfl_xor(t[i], 32, 64));
    }

    float* op = out + ((size_t)batch * NPTS + n) * 21;
    if ((lane & 15) == 0) {
        int j = lane >> 4;
#pragma unroll
        for (int i = 0; i < 4; ++i)
            op[i * 4 + j] = m16[i];
    }
    if (lane == 0 || lane == 32) {
        int j2 = lane >> 5;
        op[16 + 0 * 2 + j2] = fmaxf(t[0], t[1]);
        op[16 + 1 * 2 + j2] = fmaxf(t[2], t[3]);
    }
    if (lane == 0) {
        op[20] = fmaxf(fmaxf(u[0], u[1]), fmaxf(u[2], u[3]));
    }
}

extern "C" void kernel_launch(void* const* d_in, const int* in_sizes, int n_in,
                              void* d_out, int out_size, void* d_ws, size_t ws_size,
                              hipStream_t stream) {
    const float* x  = (const float*)d_in[0];
    const float* w1 = (const float*)d_in[1];
    const float* b1 = (const float*)d_in[2];
    const float* w2 = (const float*)d_in[3];
    const float* b2 = (const float*)d_in[4];
    const float* w3 = (const float*)d_in[5];
    const float* b3 = (const float*)d_in[6];
    float* out = (float*)d_out;
    float* ws  = (float*)d_ws;

    prep1_kernel<<<CCH, CCH, 0, stream>>>(w1, b1, w2, b2, ws);
    prep2_kernel<<<CCH, CCH, 0, stream>>>(w3, b3, ws);

    int Bp = in_sizes[0] / (NPTS * 3);             // B*T = 4
    pointsift_kernel<<<Bp * (NPTS / 8), 512, 0, stream>>>(x, ws, out);
}

// Round 5
// 26.829 us; speedup vs baseline: 1.9433x; 1.1216x over previous
//
#include <hip/hip_runtime.h>

#define NPTS 2048
#define CCH  256
#define CAP  320          // per-wave compaction capacity
#define CAPU (CAP - 64)   // safe threshold: final cnt <= CAPU guarantees complete list

// ---- DPP cross-lane helpers (VALU pipe, no LDS) ----
template <int CTRL>
__device__ __forceinline__ float dppf(float v) {
    return __int_as_float(__builtin_amdgcn_update_dpp(
        0, __float_as_int(v), CTRL, 0xF, 0xF, true));
}
__device__ __forceinline__ float row16_max(float v) {
    v = fmaxf(v, dppf<0xB1>(v));
    v = fmaxf(v, dppf<0x4E>(v));
    v = fmaxf(v, dppf<0x141>(v));
    v = fmaxf(v, dppf<0x140>(v));
    return v;
}
__device__ __forceinline__ float row16_min(float v) {
    v = fminf(v, dppf<0xB1>(v));
    v = fminf(v, dppf<0x4E>(v));
    v = fminf(v, dppf<0x141>(v));
    v = fminf(v, dppf<0x140>(v));
    return v;
}
__device__ __forceinline__ float row16_sum(float v) {
    v += dppf<0xB1>(v);
    v += dppf<0x4E>(v);
    v += dppf<0x141>(v);
    v += dppf<0x140>(v);
    return v;
}
__device__ __forceinline__ float wave_sum(float v) {
    v = row16_sum(v);
    v += __shfl_xor(v, 16, 64);
    v += __shfl_xor(v, 32, 64);
    return v;
}

// ws layout (floats): [0..767] W_eff (256x3 row-major), [768..1023] b_eff

// ---------------------------------------------------------------------------
// Merged prep: one kernel, 256 blocks x 256 threads.
// Block o: M[o][c] = sum_k W3[o][k]*W2[k][c]  (W3 row via LDS broadcast,
// W2 reads coalesced). Then W_eff[o][j] = sum_c M[o][c]*W1[c][j],
// b_eff[o] = sum_c M[o][c]*b1[c] + sum_c W3[o][c]*b2[c] + b3[o].
// (Re-association vs reference: weights-only, ~1e-6 relative.)
// ---------------------------------------------------------------------------
__global__ __launch_bounds__(256) void prep_kernel(
    const float* __restrict__ w1, const float* __restrict__ b1,
    const float* __restrict__ w2, const float* __restrict__ b2,
    const float* __restrict__ w3, const float* __restrict__ b3,
    float* __restrict__ ws)
{
    __shared__ float  w3row[CCH];
    __shared__ float4 wpart[4];
    int o = blockIdx.x, c = threadIdx.x;

    float w3c = w3[o * CCH + c];         // coalesced
    w3row[c] = w3c;
    __syncthreads();

    // M[o][c] with 4 partial accumulators for ILP
    float a0 = 0.f, a1 = 0.f, a2 = 0.f, a3 = 0.f;
    const float* w2c = w2 + c;
    for (int k = 0; k < CCH; k += 4) {
        a0 = fmaf(w3row[k + 0], w2c[(k + 0) * CCH], a0);
        a1 = fmaf(w3row[k + 1], w2c[(k + 1) * CCH], a1);
        a2 = fmaf(w3row[k + 2], w2c[(k + 2) * CCH], a2);
        a3 = fmaf(w3row[k + 3], w2c[(k + 3) * CCH], a3);
    }
    float acc = (a0 + a1) + (a2 + a3);   // M[o][c]

    float4 v = make_float4(acc * w1[c * 3 + 0],
                           acc * w1[c * 3 + 1],
                           acc * w1[c * 3 + 2],
                           fmaf(acc, b1[c], w3c * b2[c]));
    v.x = wave_sum(v.x);
    v.y = wave_sum(v.y);
    v.z = wave_sum(v.z);
    v.w = wave_sum(v.w);
    if ((c & 63) == 0) wpart[c >> 6] = v;
    __syncthreads();
    if (c == 0) {
        float4 p0 = wpart[0], p1 = wpart[1], p2 = wpart[2], p3 = wpart[3];
        ws[o * 3 + 0] = (p0.x + p1.x) + (p2.x + p3.x);
        ws[o * 3 + 1] = (p0.y + p1.y) + (p2.y + p3.y);
        ws[o * 3 + 2] = (p0.z + p1.z) + (p2.z + p3.z);
        ws[3 * CCH + o] = (p0.w + p1.w) + (p2.w + p3.w) + b3[o];
    }
}

// ---------------------------------------------------------------------------
// pointsift: 1024 threads = 16 waves = 16 points/block; grid = Bp*128.
// LDS: 32 KB coords (float4) + 16x320 u16 compaction lists = 42.75 KB.
// No forced VGPR cap (block size implies <=128); single barrier.
// ---------------------------------------------------------------------------
__global__ __launch_bounds__(1024) void pointsift_kernel(
    const float* __restrict__ x,   // [Bp, NPTS, 3]
    const float* __restrict__ ws,  // W_eff[256*3] then b_eff[256]
    float* __restrict__ out)       // [Bp, NPTS, 21]
{
    __shared__ float4 sx4[NPTS];                   // 32 KB
    __shared__ unsigned short slist[16][CAP];      // 10 KB

    int batch = blockIdx.x >> 7;                   // 128 blocks per batch
    int n0    = (blockIdx.x & 127) * 16;
    const float* xb = x + (size_t)batch * NPTS * 3;

    for (int i = threadIdx.x; i < NPTS; i += 1024) {
        float3 p = *(const float3*)(xb + 3 * i);
        sx4[i] = make_float4(p.x, p.y, p.z, 0.f);
    }

    int wave = threadIdx.x >> 6;
    int lane = threadIdx.x & 63;
    int n = n0 + wave;

    float3 cpt = *(const float3*)(xb + 3 * n);     // global, pre-barrier OK
    float cx = cpt.x, cy = cpt.y, cz = cpt.z;

    __syncthreads();                               // sx4 ready

    unsigned short* slw = slist[wave];

    // ---- pass 1: validity + wave compaction (LDS reads, slim bookkeeping) ----
    unsigned cnt = 0;
#pragma unroll 4
    for (int m = lane; m < NPTS; m += 64) {
        float4 p = sx4[m];
        float dx = p.x - cx, dy = p.y - cy, dz = p.z - cz;
        // bit-match numpy: (dx*dx + dy*dy) + dz*dz, no FMA contraction
        float d2 = __fadd_rn(__fadd_rn(__fmul_rn(dx, dx), __fmul_rn(dy, dy)),
                             __fmul_rn(dz, dz));
        bool valid = (d2 > 1e-10f) && (d2 < 0.0625f);
        unsigned long long mask = __ballot(valid);
        if (valid && cnt <= CAPU) {                // cnt uniform; no per-lane cap check
            unsigned below = __builtin_amdgcn_mbcnt_hi(
                (unsigned)(mask >> 32),
                __builtin_amdgcn_mbcnt_lo((unsigned)mask, 0u));
            slw[cnt + below] = (unsigned short)m;
        }
        cnt += (unsigned)__popcll(mask);
    }

    // ---- pass 2: per-octant best (strict <, ascending m per lane) ----
    float bd[8];
    int   bi[8];
#pragma unroll
    for (int i = 0; i < 8; ++i) { bd[i] = __builtin_inff(); bi[i] = n; }

    if (cnt <= CAPU) {                             // complete list guaranteed
        int cn = (int)cnt;
        for (int t = lane; t < cn; t += 64) {
            int m = slw[t];
            float4 p = sx4[m];
            float dx = p.x - cx, dy = p.y - cy, dz = p.z - cz;
            float d2 = __fadd_rn(__fadd_rn(__fmul_rn(dx, dx), __fmul_rn(dy, dy)),
                                 __fmul_rn(dz, dz));
            // exact octant per reference: trunc(d+1.0) in {0,1}
            int oct = 4 * (int)(dx + 1.0f) + 2 * (int)(dy + 1.0f) + (int)(dz + 1.0f);
#pragma unroll
            for (int i = 0; i < 8; ++i) {
                bool upd = (oct == i) && (d2 < bd[i]);
                bd[i] = upd ? d2 : bd[i];
                bi[i] = upd ? m : bi[i];
            }
        }
    } else {
        // astronomically rare (needs 256+ valid; E=134, sigma~11); exact fallback
        for (int m = lane; m < NPTS; m += 64) {
            float4 p = sx4[m];
            float dx = p.x - cx, dy = p.y - cy, dz = p.z - cz;
            float d2 = __fadd_rn(__fadd_rn(__fmul_rn(dx, dx), __fmul_rn(dy, dy)),
                                 __fmul_rn(dz, dz));
            bool valid = (d2 > 1e-10f) && (d2 < 0.0625f);
            int oct = 4 * (int)(dx + 1.0f) + 2 * (int)(dy + 1.0f) + (int)(dz + 1.0f);
#pragma unroll
            for (int i = 0; i < 8; ++i) {
                bool upd = valid && (oct == i) && (d2 < bd[i]);
                bd[i] = upd ? d2 : bd[i];
                bi[i] = upd ? m : bi[i];
            }
        }
    }

    // ---- cross-lane argmin: DPP min + 2 swizzles; exact first-min tie-break ----
    int nidx[8];
#pragma unroll
    for (int i = 0; i < 8; ++i) {
        float mv = row16_min(bd[i]);
        mv = fminf(mv, __shfl_xor(mv, 16, 64));
        mv = fminf(mv, __shfl_xor(mv, 32, 64));
        unsigned long long mk = __ballot(bd[i] == mv);   // wave-uniform
        if (__popcll(mk) == 1) {
            nidx[i] = __builtin_amdgcn_readlane(bi[i], (int)__builtin_ctzll(mk));
        } else {
            // ties (or empty octant: mv=inf, all lanes match, bi=n everywhere)
            int mm = (bd[i] == mv) ? bi[i] : 0x7FFFFFFF;
#pragma unroll
            for (int s = 32; s > 0; s >>= 1) {
                int o = __shfl_xor(mm, s, 64);
                mm = o < mm ? o : mm;
            }
            nidx[i] = mm;
        }
    }

    // ---- fused affine + SPP: lane handles channels 4*lane..4*lane+3 ----
    // W_eff rows for these channels = 48B at ws + lane*48 -> 3x dwordx4
    const float4* wsv = (const float4*)ws;
    float4 wa = wsv[lane * 3 + 0];
    float4 wb = wsv[lane * 3 + 1];
    float4 wc = wsv[lane * 3 + 2];
    float4 be = ((const float4*)(ws + 3 * CCH))[lane];
    float w[4][3] = {{wa.x, wa.y, wa.z}, {wa.w, wb.x, wb.y},
                     {wb.z, wb.w, wc.x}, {wc.y, wc.z, wc.w}};
    float bev[4] = {be.x, be.y, be.z, be.w};

    float m16[4];
#pragma unroll
    for (int i = 0; i < 4; ++i) m16[i] = -__builtin_inff();
#pragma unroll
    for (int k = 0; k < 8; ++k) {
        float4 p = sx4[nidx[k]];                   // wave-uniform -> broadcast
        float gx = p.x - cx, gy = p.y - cy, gz = p.z - cz;
#pragma unroll
        for (int q = 0; q < 4; ++q) {
            float h = fmaf(gx, w[q][0], fmaf(gy, w[q][1], fmaf(gz, w[q][2], bev[q])));
            m16[k >> 1] = fmaxf(m16[k >> 1], h);
        }
    }

    float t[4], u[4];
#pragma unroll
    for (int i = 0; i < 4; ++i) {
        m16[i] = row16_max(m16[i]);
        t[i] = fmaxf(m16[i], __shfl_xor(m16[i], 16, 64));
        u[i] = fmaxf(t[i], __shfl_xor(t[i], 32, 64));
    }

    float* op = out + ((size_t)batch * NPTS + n) * 21;
    if ((lane & 15) == 0) {
        int j = lane >> 4;
#pragma unroll
        for (int i = 0; i < 4; ++i)
            op[i * 4 + j] = m16[i];
    }
    if (lane == 0 || lane == 32) {
        int j2 = lane >> 5;
        op[16 + 0 * 2 + j2] = fmaxf(t[0], t[1]);
        op[16 + 1 * 2 + j2] = fmaxf(t[2], t[3]);
    }
    if (lane == 0) {
        op[20] = fmaxf(fmaxf(u[0], u[1]), fmaxf(u[2], u[3]));
    }
}

extern "C" void kernel_launch(void* const* d_in, const int* in_sizes, int n_in,
                              void* d_out, int out_size, void* d_ws, size_t ws_size,
                              hipStream_t stream) {
    const float* x  = (const float*)d_in[0];
    const float* w1 = (const float*)d_in[1];
    const float* b1 = (const float*)d_in[2];
    const float* w2 = (const float*)d_in[3];
    const float* b2 = (const float*)d_in[4];
    const float* w3 = (const float*)d_in[5];
    const float* b3 = (const float*)d_in[6];
    float* out = (float*)d_out;
    float* ws  = (float*)d_ws;

    prep_kernel<<<CCH, CCH, 0, stream>>>(w1, b1, w2, b2, w3, b3, ws);

    int Bp = in_sizes[0] / (NPTS * 3);             // B*T = 4
    pointsift_kernel<<<Bp * (NPTS / 16), 1024, 0, stream>>>(x, ws, out);
}